// Round 3
// baseline (583.244 us; speedup 1.0000x reference)
//
#include <hip/hip_runtime.h>

// Tensor-product expansion: out[c,i,j,k,l] = tb[c,0,i]*tb[c,1,j]*tb[c,2,k]*tb[c,3,l]
// where tb = tensor + bias.  C=2048, N=4, L=16.  Output 2048*65536 fp32 = 512 MiB.
//
// R2 finding: cached vs nt stores flat; kernel ~170us (= 1 GiB @ 6.3 TB/s) while
// fillBufferAligned proves 6.25 TB/s on the same buffer.  Remaining structural
// difference vs fill: fill is a device-wide grid-stride SWEEP (one sliding ~8 MiB
// window, max DRAM row locality); ours was 2048 concurrent per-block streams.
//
// R3: grid-stride sweep.  G = 2048*256 = 524288 threads; per-iter f4-stride = G
// => float-stride 2097152 = 32 full channels, so each thread's (i,j,k,l) is
// CONSTANT and only c advances by 32/iter.  Factor reads are L1/L2 broadcasts
// from the 512 KiB (tensor,bias) tables; write stream becomes fill-shaped.

#define NTHREADS 524288   // 2048 blocks x 256 threads = exactly 8 blocks/CU, full occupancy
#define NITER    64       // 33554432 f4 elements / NTHREADS

typedef float f4 __attribute__((ext_vector_type(4)));

__global__ __launch_bounds__(256) void
tpe_sweep(const float* __restrict__ tensor,
          const float* __restrict__ bias,
          float* __restrict__ out) {
    const int tid = blockIdx.x * 256 + threadIdx.x;   // 0..524287

    // flat float index f = tid*4 + n*2097152
    //   c = f>>16 = (tid>>14) + 32n ; within-c offset w = (tid&16383)*4 (constant)
    const int c0 = tid >> 14;                // 0..31
    const int w  = (tid & 16383) * 4;        // 0..65532
    const int i  = w >> 12;                  // factor 0 index
    const int j  = (w >> 8) & 15;            // factor 1 index
    const int k  = (w >> 4) & 15;            // factor 2 index
    const int lq = w & 15;                   // factor 3 quad base (0,4,8,12) - 16B aligned

    const float* tp = tensor + c0 * 64;
    const float* bp = bias   + c0 * 64;
    f4* op = (f4*)out + tid;

    #pragma unroll 4
    for (int n = 0; n < NITER; ++n) {
        // wave-uniform / broadcast loads from the 512 KiB factor tables (L1/L2 hits)
        const float a  = tp[i]      + bp[i];
        const float b  = tp[16 + j] + bp[16 + j];
        const float ck = tp[32 + k] + bp[32 + k];
        const f4 t4 = *(const f4*)(tp + 48 + lq);
        const f4 b4 = *(const f4*)(bp + 48 + lq);

        const float abc = a * b * ck;
        f4 o;
        o.x = abc * (t4.x + b4.x);
        o.y = abc * (t4.y + b4.y);
        o.z = abc * (t4.z + b4.z);
        o.w = abc * (t4.w + b4.w);
        *op = o;                              // 16B/lane, 1 KiB/wave, device-wide sweep

        tp += 2048; bp += 2048;               // c += 32
        op += NTHREADS;                       // + 8 MiB / 16B
    }
}

extern "C" void kernel_launch(void* const* d_in, const int* in_sizes, int n_in,
                              void* d_out, int out_size, void* d_ws, size_t ws_size,
                              hipStream_t stream) {
    const float* tensor = (const float*)d_in[0];
    const float* bias   = (const float*)d_in[1];
    float* out = (float*)d_out;
    tpe_sweep<<<NTHREADS / 256, 256, 0, stream>>>(tensor, bias, out);
}